// Round 4
// baseline (85.613 us; speedup 1.0000x reference)
//
#include <hip/hip_runtime.h>

// Soft decision tree DEPTH=8, 255 internal nodes (heap order), 256 leaves,
// 10 classes, B=131072, 32 feats. fp32 in/out.
//
// R8 = R7 (MFMA leaf->class reduction, lane-resident nodes via v_readlane,
// swizzled f16 P tile) restructured for OCCUPANCY, which R7 starved:
//   - R7 was 66.7KB LDS -> 2 blocks/CU = 2 waves/SIMD; a latency-chain
//     workload (ds_read -> exp2 -> rcp per depth) can't hide at 2 waves.
//   - 2 threads/row (RPB=128, h=t>>7): per-thread evals 255 -> 128.
//   - P staged 32 leaves per half per pass (4 passes): s_P [128][64] f16
//     = 16KB; s_xT [32][129] f32 = 16.5KB; s_lc 1KB -> 33.9KB total
//     -> 4 blocks/CU = 16 waves; launch_bounds(256,4) caps VGPR at 128.
//   - node regs re-banked so no member select: ta=nodes 0..62 (lane=n),
//     tb=63..126 (lane=n-63), t7=own half's depth-7 (h baked in at load);
//     readlane with runtime-uniform lane. Depth-7 lane = 16p+4s+u.
//   - B onehot fragments rebuilt per pass from s_lc (8 VGPR, not 32).
// MFMA conventions byte-identical to R7 (verified passing): A k-group
// (lane>>4)*8, B built with same k-labeling, C/D col=lane&15,
// row=(lane>>4)*4+reg, XOR swizzle ((r^(r>>3))&7)<<4 on 128B rows.

#define NFEAT 32
#define NCLS  10
#define TPB   256
#define RPB   128          // rows per block (2 threads per row)
#define XPITCH 129         // padded f32 pitch for s_xT
#define L2E   1.4426950408889634f

typedef _Float16 f16x8 __attribute__((ext_vector_type(8)));
typedef float    f32x4 __attribute__((ext_vector_type(4)));

__device__ __forceinline__ float fexp2(float z) {
#if __has_builtin(__builtin_amdgcn_exp2f)
  return __builtin_amdgcn_exp2f(z);
#else
  return exp2f(z);
#endif
}
__device__ __forceinline__ float frcp(float z) {
#if __has_builtin(__builtin_amdgcn_rcpf)
  return __builtin_amdgcn_rcpf(z);
#else
  return 1.0f / z;
#endif
}
__device__ __forceinline__ float rlf(float v, int lane) {
  return __int_as_float(__builtin_amdgcn_readlane(__float_as_int(v), lane));
}
__device__ __forceinline__ int rli(int v, int lane) {
  return __builtin_amdgcn_readlane(v, lane);
}

// Lane-resident node records (thresholds pre-scaled by log2e).
struct NodeRegs {
  float ta, tb, t7;   // nodes 0..62 (lane=n) / 63..126 (lane=n-63) / depth-7 own half
  int   fa, fb, f7;
};

// sigmoid(x-t): e = exp2(t2 - x2); a = 1/(1+e); pr = p*a; pl = pr*e.
__device__ __forceinline__ void sig(float th, int ft, const float* xT, int row,
                                    float p, float& pl, float& pr) {
  const float x2 = xT[ft * XPITCH + row];
  const float e  = fexp2(th - x2);
  const float a  = frcp(1.0f + e);
  pr = p * a;
  pl = pr * e;
}
__device__ __forceinline__ void evalA(const NodeRegs& R, const float* xT, int n,
                                      int row, float p, float& pl, float& pr) {
  sig(rlf(R.ta, n), rli(R.fa, n), xT, row, p, pl, pr);
}
__device__ __forceinline__ void evalB(const NodeRegs& R, const float* xT, int n,
                                      int row, float p, float& pl, float& pr) {
  sig(rlf(R.tb, n - 63), rli(R.fb, n - 63), xT, row, p, pl, pr);
}
// depth-7 node at own-half lane index l7 -> packed half2 (low = left leaf)
__device__ __forceinline__ unsigned leafpair7(const NodeRegs& R, const float* xT,
                                              int l7, int row, float p) {
  float pl, pr;
  sig(rlf(R.t7, l7), rli(R.f7, l7), xT, row, p, pl, pr);
  const _Float16 hl = (_Float16)pl, hr = (_Float16)pr;
  return ((unsigned)__builtin_bit_cast(unsigned short, hr) << 16) |
          (unsigned)__builtin_bit_cast(unsigned short, hl);
}

// Depth-5 subtree: 8 leaves -> one swizzled b128 store. n5 in 31..62 (bank A),
// children 63..126 (bank B), l7b = depth-7 own-half lane base.
__device__ __forceinline__ void d5block(const NodeRegs& R, const float* xT,
                                        int row, int n5, int l7b, float p,
                                        char* rowp, int boff) {
  float pl, pr;
  evalA(R, xT, n5, row, p, pl, pr);
  float qll, qlr, qrl, qrr;
  evalB(R, xT, 2 * n5 + 1, row, pl, qll, qlr);
  evalB(R, xT, 2 * n5 + 2, row, pr, qrl, qrr);
  uint4 u;
  u.x = leafpair7(R, xT, l7b + 0, row, qll);
  u.y = leafpair7(R, xT, l7b + 1, row, qlr);
  u.z = leafpair7(R, xT, l7b + 2, row, qrl);
  u.w = leafpair7(R, xT, l7b + 3, row, qrr);
  *(uint4*)(rowp + boff) = u;
}

__global__ __launch_bounds__(TPB, 4)
void dt_kernel(const float* __restrict__ x,
               const float* __restrict__ thr,
               const int*   __restrict__ feats,
               const int*   __restrict__ leafc,
               float*       __restrict__ out) {
  __shared__ float s_xT[NFEAT * XPITCH];           // transposed x, *log2e (16.5KB)
  __shared__ __align__(16) char s_P[RPB * 128];    // P slice, f16, swizzled (16KB)
  __shared__ int s_lc[256];                        // leaf classes (1KB)

  const int t    = threadIdx.x;
  const int lane = t & 63;
  const int row  = t & (RPB - 1);
  const int h    = t >> 7;                         // wave-uniform half select

  // --- lane-resident node records ---
  NodeRegs R;
  R.ta = thr[lane] * L2E;
  R.tb = thr[63 + lane] * L2E;
  R.t7 = thr[127 + 64 * h + lane] * L2E;
  R.fa = feats[lane];
  R.fb = feats[63 + lane];
  R.f7 = feats[127 + 64 * h + lane];

  // --- stage x (coalesced float4, transposed, padded pitch) + leafc ---
  const float4* xg = (const float4*)x + (size_t)blockIdx.x * (RPB * NFEAT / 4);
#pragma unroll
  for (int k = 0; k < 4; ++k) {
    const int i4 = k * TPB + t;                    // 0..1023
    const float4 v = xg[i4];
    const int r  = i4 >> 3;
    const int c0 = (i4 & 7) * 4;
    s_xT[(c0 + 0) * XPITCH + r] = v.x * L2E;
    s_xT[(c0 + 1) * XPITCH + r] = v.y * L2E;
    s_xT[(c0 + 2) * XPITCH + r] = v.z * L2E;
    s_xT[(c0 + 3) * XPITCH + r] = v.w * L2E;
  }
  s_lc[t] = leafc[t];

  __syncthreads();

  // --- top: depths 0..2 of this half -> 4 depth-3 probs (nodes 7+4h+p) ---
  float pl, pr;
  evalA(R, s_xT, 0, row, 1.0f, pl, pr);
  const float pd1 = h ? pr : pl;
  evalA(R, s_xT, 1 + h, row, pd1, pl, pr);
  const float pA = pl, pB = pr;
  float pm0, pm1, pm2, pm3;
  evalA(R, s_xT, 3 + 2 * h, row, pA, pm0, pm1);
  evalA(R, s_xT, 4 + 2 * h, row, pB, pm2, pm3);

  const int swz   = ((row ^ (row >> 3)) & 7) << 4;
  char* rowp      = s_P + row * 128;
  const int hofs  = h * 64;                        // byte base of this half's chunk
  const int wv    = t >> 6;                        // wave id 0..3
  const int col16 = lane & 15;
  const int kgrpB = (lane >> 4) * 16;

  f32x4 acc0 = {0.f, 0.f, 0.f, 0.f};
  f32x4 acc1 = {0.f, 0.f, 0.f, 0.f};

#pragma unroll 1
  for (int p = 0; p < 4; ++p) {
    // --- DFS: depth-3 subtree (32 leaves) of this half ---
    const float p3 = (p == 0) ? pm0 : (p == 1) ? pm1 : (p == 2) ? pm2 : pm3;
    const int n3 = 7 + 4 * h + p;
    float p4l, p4r;
    evalA(R, s_xT, n3, row, p3, p4l, p4r);
    float q0, q1, q2, q3;
    evalA(R, s_xT, 2 * n3 + 1, row, p4l, q0, q1);
    evalA(R, s_xT, 2 * n3 + 2, row, p4r, q2, q3);
    const int n5b = 4 * n3 + 3;                    // first depth-5 node
#pragma unroll
    for (int s = 0; s < 4; ++s) {
      const float q = (s == 0) ? q0 : (s == 1) ? q1 : (s == 2) ? q2 : q3;
      d5block(R, s_xT, row, n5b + s, 16 * p + 4 * s, q, rowp,
              (hofs + s * 16) ^ swz);
    }

    __syncthreads();                               // P slice ready

    // --- B onehot fragments for this pass (rebuilt from s_lc) ---
    f16x8 Bf0, Bf1;
    {
      const int kb = (lane >> 4) * 8;
      const int4 cA0 = *(const int4*)&s_lc[p * 32 + kb];
      const int4 cB0 = *(const int4*)&s_lc[p * 32 + kb + 4];
      uint4 u0;
      u0.x = ((cA0.x == col16) ? 0x3C00u : 0u) | (((cA0.y == col16) ? 0x3C00u : 0u) << 16);
      u0.y = ((cA0.z == col16) ? 0x3C00u : 0u) | (((cA0.w == col16) ? 0x3C00u : 0u) << 16);
      u0.z = ((cB0.x == col16) ? 0x3C00u : 0u) | (((cB0.y == col16) ? 0x3C00u : 0u) << 16);
      u0.w = ((cB0.z == col16) ? 0x3C00u : 0u) | (((cB0.w == col16) ? 0x3C00u : 0u) << 16);
      Bf0 = __builtin_bit_cast(f16x8, u0);
      const int4 cA1 = *(const int4*)&s_lc[128 + p * 32 + kb];
      const int4 cB1 = *(const int4*)&s_lc[128 + p * 32 + kb + 4];
      uint4 u1;
      u1.x = ((cA1.x == col16) ? 0x3C00u : 0u) | (((cA1.y == col16) ? 0x3C00u : 0u) << 16);
      u1.y = ((cA1.z == col16) ? 0x3C00u : 0u) | (((cA1.w == col16) ? 0x3C00u : 0u) << 16);
      u1.z = ((cB1.x == col16) ? 0x3C00u : 0u) | (((cB1.y == col16) ? 0x3C00u : 0u) << 16);
      u1.w = ((cB1.z == col16) ? 0x3C00u : 0u) | (((cB1.w == col16) ? 0x3C00u : 0u) << 16);
      Bf1 = __builtin_bit_cast(f16x8, u1);
    }

    // --- 2 row-tiles per wave x 2 K=32 chunks ---
#pragma unroll
    for (int i = 0; i < 2; ++i) {
      const int arow = (wv * 2 + i) * 16 + col16;
      const int aswz = ((arow ^ (arow >> 3)) & 7) << 4;
      const char* ap = s_P + arow * 128;
      const f16x8 a0 = *(const f16x8*)(ap + ((kgrpB)      ^ aswz));
      const f16x8 a1 = *(const f16x8*)(ap + ((kgrpB + 64) ^ aswz));
      if (i == 0) {
        acc0 = __builtin_amdgcn_mfma_f32_16x16x32_f16(a0, Bf0, acc0, 0, 0, 0);
        acc0 = __builtin_amdgcn_mfma_f32_16x16x32_f16(a1, Bf1, acc0, 0, 0, 0);
      } else {
        acc1 = __builtin_amdgcn_mfma_f32_16x16x32_f16(a0, Bf0, acc1, 0, 0, 0);
        acc1 = __builtin_amdgcn_mfma_f32_16x16x32_f16(a1, Bf1, acc1, 0, 0, 0);
      }
    }

    __syncthreads();                               // P consumed
  }

  // --- epilogue: D layout col=lane&15, row=(lane>>4)*4+reg (verified) ---
  if (col16 < NCLS) {
    const int r4 = (lane >> 4) * 4;
#pragma unroll
    for (int i = 0; i < 2; ++i) {
      const size_t gr = (size_t)blockIdx.x * RPB + (wv * 2 + i) * 16 + r4;
#pragma unroll
      for (int j = 0; j < 4; ++j) {
        out[(gr + j) * NCLS + col16] = (i == 0) ? acc0[j] : acc1[j];
      }
    }
  }
}

extern "C" void kernel_launch(void* const* d_in, const int* in_sizes, int n_in,
                              void* d_out, int out_size, void* d_ws, size_t ws_size,
                              hipStream_t stream) {
  const float* x     = (const float*)d_in[0];
  const float* thr   = (const float*)d_in[1];
  const int*   feats = (const int*)d_in[2];
  const int*   leafc = (const int*)d_in[3];
  float*       out   = (float*)d_out;

  const int B    = in_sizes[0] / NFEAT;        // 131072
  const int grid = B / RPB;                    // 1024

  dt_kernel<<<grid, TPB, 0, stream>>>(x, thr, feats, leafc, out);
}

// Round 6
// 82.542 us; speedup vs baseline: 1.0372x; 1.0372x over previous
//
#include <hip/hip_runtime.h>

// Soft decision tree DEPTH=8, 255 internal nodes (heap order), 256 leaves,
// 10 classes, B=131072, 32 feats. fp32 in/out.
//
// R9b = R9 resubmitted verbatim (R5's bench failed on container acquire, not
// on the kernel; source re-audited for OOB/deadlock — none found).
//
// R9: attack cost-per-eval. Evidence: R4 (DS-RMW), R7 (MFMA, 2 blk/CU) and
// R8 (MFMA, 4 blk/CU) all measure ~25us with the SAME 512 node-evals/SIMD
// -> eval issue/latency cost is the invariant bottleneck, occupancy is not.
// Three reductions, numerics preserved:
//   1. e = 2^(t2-x2) factored as (2^t2)*(2^-x2): node regs hold 2^t2,
//      s_xT holds w = 2^-x2 (exp2 at staging). Per-eval trans 2 -> 1 (rcp),
//      chain loses the exp2 hop: ds_read -> fma(tpow,w,1) -> rcp -> mul.
//   2. pl = p - pr (== p*(1-a) exactly); e never materialized.
//   3. TWO rows per thread (TPB=256, RPB=256, h-split kept): node readlanes
//      shared, the two x-gathers fuse into ONE ds_read_b64 (XPITCH=258 even
//      keeps 8B alignment; 4 lanes/bank = b64 minimum, conflict-free).
//      DS ops/eval-pair halved, 2x ILP on every chain.
// LDS = s_xT 32x258 f32 (33KB) + s_P 256x128B (32KB) + s_lc 1KB = 66.8KB
// -> 2 blocks/CU (R7 vs R8 proved 2 vs 4 blocks is perf-neutral here).
// MFMA conventions byte-identical to verified R7/R8: A k-group (lane>>4)*8,
// XOR swizzle ((r^(r>>3))&7)<<4 on 128B rows, C/D col=lane&15,
// row=(lane>>4)*4+reg, Bf0 from s_lc[32p+kb], Bf1 from s_lc[128+32p+kb].

#define NFEAT 32
#define NCLS  10
#define TPB   256
#define RPB   256          // rows per block (2 rows/thread, 2 thread-halves/row)
#define XPITCH 258         // padded f32 pitch, EVEN: row-pair b64 stays aligned
#define L2E   1.4426950408889634f

typedef _Float16 f16x8 __attribute__((ext_vector_type(8)));
typedef float    f32x4 __attribute__((ext_vector_type(4)));

__device__ __forceinline__ float fexp2(float z) {
#if __has_builtin(__builtin_amdgcn_exp2f)
  return __builtin_amdgcn_exp2f(z);
#else
  return exp2f(z);
#endif
}
__device__ __forceinline__ float frcp(float z) {
#if __has_builtin(__builtin_amdgcn_rcpf)
  return __builtin_amdgcn_rcpf(z);
#else
  return 1.0f / z;
#endif
}
__device__ __forceinline__ float rlf(float v, int lane) {
  return __int_as_float(__builtin_amdgcn_readlane(__float_as_int(v), lane));
}
__device__ __forceinline__ int rli(int v, int lane) {
  return __builtin_amdgcn_readlane(v, lane);
}

// Lane-resident node records; thresholds stored as tpow = 2^(thr*log2e).
struct NodeRegs {
  float ta, tb, t7;   // nodes 0..62 (lane=n) / 63..126 (lane=n-63) / d7 own half
  int   fa, fb, f7;
};

// Paired sigmoid for rows (2rp, 2rp+1):
//   a = 1/(1 + tpow*w);  pr = p*a;  pl = p - pr  (== p*(1-a)).
__device__ __forceinline__ void sig2(float tpow, int ft, const float* xT, int rp,
                                     float p0, float p1,
                                     float& l0, float& r0, float& l1, float& r1) {
  const float2 w = *(const float2*)&xT[ft * XPITCH + 2 * rp];  // ds_read_b64
  const float a0 = frcp(__builtin_fmaf(tpow, w.x, 1.0f));
  const float a1 = frcp(__builtin_fmaf(tpow, w.y, 1.0f));
  r0 = p0 * a0;  l0 = p0 - r0;
  r1 = p1 * a1;  l1 = p1 - r1;
}
__device__ __forceinline__ void evalA2(const NodeRegs& R, const float* xT, int n,
                                       int rp, float p0, float p1,
                                       float& l0, float& r0, float& l1, float& r1) {
  sig2(rlf(R.ta, n), rli(R.fa, n), xT, rp, p0, p1, l0, r0, l1, r1);
}
__device__ __forceinline__ void evalB2(const NodeRegs& R, const float* xT, int n,
                                       int rp, float p0, float p1,
                                       float& l0, float& r0, float& l1, float& r1) {
  sig2(rlf(R.tb, n - 63), rli(R.fb, n - 63), xT, rp, p0, p1, l0, r0, l1, r1);
}
// depth-7 node (own-half lane l7): packed half2 per row, low = LEFT leaf.
__device__ __forceinline__ void leafpair7x2(const NodeRegs& R, const float* xT,
                                            int l7, int rp, float p0, float p1,
                                            unsigned& u0, unsigned& u1) {
  float l0, r0, l1, r1;
  sig2(rlf(R.t7, l7), rli(R.f7, l7), xT, rp, p0, p1, l0, r0, l1, r1);
  const _Float16 hl0 = (_Float16)l0, hr0 = (_Float16)r0;
  const _Float16 hl1 = (_Float16)l1, hr1 = (_Float16)r1;
  u0 = ((unsigned)__builtin_bit_cast(unsigned short, hr0) << 16) |
        (unsigned)__builtin_bit_cast(unsigned short, hl0);
  u1 = ((unsigned)__builtin_bit_cast(unsigned short, hr1) << 16) |
        (unsigned)__builtin_bit_cast(unsigned short, hl1);
}

// Depth-5 subtree (8 leaves) for BOTH rows -> two swizzled b128 stores.
// n5 in 31..62 (bank A), children 63..126 (bank B), l7b = d7 own-half base.
__device__ __forceinline__ void d5block2(const NodeRegs& R, const float* xT,
                                         int rp, int n5, int l7b,
                                         float p0, float p1,
                                         char* rowp0, char* rowp1,
                                         int boff0, int boff1) {
  float pl0, pr0, pl1, pr1;
  evalA2(R, xT, n5, rp, p0, p1, pl0, pr0, pl1, pr1);
  float qll0, qlr0, qll1, qlr1;
  evalB2(R, xT, 2 * n5 + 1, rp, pl0, pl1, qll0, qlr0, qll1, qlr1);
  float qrl0, qrr0, qrl1, qrr1;
  evalB2(R, xT, 2 * n5 + 2, rp, pr0, pr1, qrl0, qrr0, qrl1, qrr1);
  uint4 u0, u1;
  leafpair7x2(R, xT, l7b + 0, rp, qll0, qll1, u0.x, u1.x);
  leafpair7x2(R, xT, l7b + 1, rp, qlr0, qlr1, u0.y, u1.y);
  leafpair7x2(R, xT, l7b + 2, rp, qrl0, qrl1, u0.z, u1.z);
  leafpair7x2(R, xT, l7b + 3, rp, qrr0, qrr1, u0.w, u1.w);
  *(uint4*)(rowp0 + boff0) = u0;
  *(uint4*)(rowp1 + boff1) = u1;
}

__global__ __launch_bounds__(TPB, 2)
void dt_kernel(const float* __restrict__ x,
               const float* __restrict__ thr,
               const int*   __restrict__ feats,
               const int*   __restrict__ leafc,
               float*       __restrict__ out) {
  __shared__ __align__(16) float s_xT[NFEAT * XPITCH];  // w = 2^-x2 (33KB)
  __shared__ __align__(16) char  s_P[RPB * 128];        // P slice f16 (32KB)
  __shared__ int s_lc[256];                             // leaf classes (1KB)

  const int t    = threadIdx.x;
  const int lane = t & 63;
  const int rp   = t & 127;                 // row-pair index 0..127
  const int h    = t >> 7;                  // wave-uniform half select

  // --- lane-resident node records (tpow = 2^(thr*log2e)) ---
  NodeRegs R;
  R.ta = fexp2(thr[lane] * L2E);
  R.tb = fexp2(thr[63 + lane] * L2E);
  R.t7 = fexp2(thr[127 + 64 * h + lane] * L2E);
  R.fa = feats[lane];
  R.fb = feats[63 + lane];
  R.f7 = feats[127 + 64 * h + lane];

  // --- stage w = 2^(-x*log2e): coalesced float4, transposed ---
  const float4* xg = (const float4*)x + (size_t)blockIdx.x * (RPB * NFEAT / 4);
#pragma unroll
  for (int k = 0; k < 8; ++k) {
    const int i4 = k * TPB + t;             // 0..2047
    const float4 v = xg[i4];
    const int r  = i4 >> 3;
    const int c0 = (i4 & 7) * 4;
    s_xT[(c0 + 0) * XPITCH + r] = fexp2(-v.x * L2E);
    s_xT[(c0 + 1) * XPITCH + r] = fexp2(-v.y * L2E);
    s_xT[(c0 + 2) * XPITCH + r] = fexp2(-v.z * L2E);
    s_xT[(c0 + 3) * XPITCH + r] = fexp2(-v.w * L2E);
  }
  s_lc[t] = leafc[t];

  __syncthreads();

  // --- top: depths 0..2 of this half, both rows -> 4 depth-3 prob pairs ---
  float pl0, pr0, pl1, pr1;
  evalA2(R, s_xT, 0, rp, 1.0f, 1.0f, pl0, pr0, pl1, pr1);
  const float pd10 = h ? pr0 : pl0;
  const float pd11 = h ? pr1 : pl1;
  evalA2(R, s_xT, 1 + h, rp, pd10, pd11, pl0, pr0, pl1, pr1);
  const float pA0 = pl0, pB0 = pr0, pA1 = pl1, pB1 = pr1;
  float pm00, pm01, pm02, pm03, pm10, pm11, pm12, pm13;   // pm[row][pass]
  evalA2(R, s_xT, 3 + 2 * h, rp, pA0, pA1, pm00, pm01, pm10, pm11);
  evalA2(R, s_xT, 4 + 2 * h, rp, pB0, pB1, pm02, pm03, pm12, pm13);

  const int row0 = 2 * rp, row1 = row0 + 1;
  const int swz0 = ((row0 ^ (row0 >> 3)) & 7) << 4;
  const int swz1 = ((row1 ^ (row1 >> 3)) & 7) << 4;
  char* rowp0    = s_P + row0 * 128;
  char* rowp1    = s_P + row1 * 128;
  const int hofs = h * 64;
  const int wv   = t >> 6;
  const int col16 = lane & 15;
  const int kgrpB = (lane >> 4) * 16;

  f32x4 acc[4];
#pragma unroll
  for (int i = 0; i < 4; ++i) acc[i] = (f32x4){0.f, 0.f, 0.f, 0.f};

#pragma unroll 1
  for (int p = 0; p < 4; ++p) {
    __syncthreads();                        // prev pass's MFMA reads done

    // --- DFS: this half's 32-leaf subtree, both rows ---
    const float p30 = (p == 0) ? pm00 : (p == 1) ? pm01 : (p == 2) ? pm02 : pm03;
    const float p31 = (p == 0) ? pm10 : (p == 1) ? pm11 : (p == 2) ? pm12 : pm13;
    const int n3 = 7 + 4 * h + p;
    float p4l0, p4r0, p4l1, p4r1;
    evalA2(R, s_xT, n3, rp, p30, p31, p4l0, p4r0, p4l1, p4r1);
    float q00, q10, q01, q11, q20, q30, q21, q31;   // q[s][row]
    evalA2(R, s_xT, 2 * n3 + 1, rp, p4l0, p4l1, q00, q10, q01, q11);
    evalA2(R, s_xT, 2 * n3 + 2, rp, p4r0, p4r1, q20, q30, q21, q31);
    const int n5b = 4 * n3 + 3;
#pragma unroll
    for (int s = 0; s < 4; ++s) {
      const float a = (s == 0) ? q00 : (s == 1) ? q10 : (s == 2) ? q20 : q30;
      const float b = (s == 0) ? q01 : (s == 1) ? q11 : (s == 2) ? q21 : q31;
      d5block2(R, s_xT, rp, n5b + s, 16 * p + 4 * s, a, b, rowp0, rowp1,
               (hofs + s * 16) ^ swz0, (hofs + s * 16) ^ swz1);
    }

    __syncthreads();                        // P slice ready

    // --- B onehot fragments for this pass (rebuilt from s_lc) ---
    f16x8 Bf0, Bf1;
    {
      const int kb = (lane >> 4) * 8;
      const int4 cA0 = *(const int4*)&s_lc[p * 32 + kb];
      const int4 cB0 = *(const int4*)&s_lc[p * 32 + kb + 4];
      uint4 u0;
      u0.x = ((cA0.x == col16) ? 0x3C00u : 0u) | (((cA0.y == col16) ? 0x3C00u : 0u) << 16);
      u0.y = ((cA0.z == col16) ? 0x3C00u : 0u) | (((cA0.w == col16) ? 0x3C00u : 0u) << 16);
      u0.z = ((cB0.x == col16) ? 0x3C00u : 0u) | (((cB0.y == col16) ? 0x3C00u : 0u) << 16);
      u0.w = ((cB0.z == col16) ? 0x3C00u : 0u) | (((cB0.w == col16) ? 0x3C00u : 0u) << 16);
      Bf0 = __builtin_bit_cast(f16x8, u0);
      const int4 cA1 = *(const int4*)&s_lc[128 + p * 32 + kb];
      const int4 cB1 = *(const int4*)&s_lc[128 + p * 32 + kb + 4];
      uint4 u1;
      u1.x = ((cA1.x == col16) ? 0x3C00u : 0u) | (((cA1.y == col16) ? 0x3C00u : 0u) << 16);
      u1.y = ((cA1.z == col16) ? 0x3C00u : 0u) | (((cA1.w == col16) ? 0x3C00u : 0u) << 16);
      u1.z = ((cB1.x == col16) ? 0x3C00u : 0u) | (((cB1.y == col16) ? 0x3C00u : 0u) << 16);
      u1.w = ((cB1.z == col16) ? 0x3C00u : 0u) | (((cB1.w == col16) ? 0x3C00u : 0u) << 16);
      Bf1 = __builtin_bit_cast(f16x8, u1);
    }

    // --- 4 row-tiles per wave x 2 K=32 chunks ---
#pragma unroll
    for (int i = 0; i < 4; ++i) {
      const int arow = (wv * 4 + i) * 16 + col16;
      const int aswz = ((arow ^ (arow >> 3)) & 7) << 4;
      const char* ap = s_P + arow * 128;
      const f16x8 a0 = *(const f16x8*)(ap + ((kgrpB)      ^ aswz));
      const f16x8 a1 = *(const f16x8*)(ap + ((kgrpB + 64) ^ aswz));
      acc[i] = __builtin_amdgcn_mfma_f32_16x16x32_f16(a0, Bf0, acc[i], 0, 0, 0);
      acc[i] = __builtin_amdgcn_mfma_f32_16x16x32_f16(a1, Bf1, acc[i], 0, 0, 0);
    }
  }

  // --- epilogue: D layout col=lane&15, row=(lane>>4)*4+reg (verified) ---
  if (col16 < NCLS) {
    const int r4 = (lane >> 4) * 4;
#pragma unroll
    for (int i = 0; i < 4; ++i) {
      const size_t gr = (size_t)blockIdx.x * RPB + wv * 64 + i * 16 + r4;
#pragma unroll
      for (int j = 0; j < 4; ++j) {
        out[(gr + j) * NCLS + col16] = acc[i][j];
      }
    }
  }
}

extern "C" void kernel_launch(void* const* d_in, const int* in_sizes, int n_in,
                              void* d_out, int out_size, void* d_ws, size_t ws_size,
                              hipStream_t stream) {
  const float* x     = (const float*)d_in[0];
  const float* thr   = (const float*)d_in[1];
  const int*   feats = (const int*)d_in[2];
  const int*   leafc = (const int*)d_in[3];
  float*       out   = (float*)d_out;

  const int B    = in_sizes[0] / NFEAT;        // 131072
  const int grid = B / RPB;                    // 512

  dt_kernel<<<grid, TPB, 0, stream>>>(x, thr, feats, leafc, out);
}

// Round 7
// 81.066 us; speedup vs baseline: 1.0561x; 1.0182x over previous
//
#include <hip/hip_runtime.h>

// Soft decision tree DEPTH=8, 255 internal nodes (heap order), 256 leaves,
// 10 classes, B=131072, 32 feats. fp32 in/out.
//
// R10: quarter-tree job split. Evidence: R8 (16 waves/CU, ILP=1) = 25.6us,
// R9 (8 waves/CU, ILP=2, cheap eval) = 22.5us, both >> ~8us throughput
// arithmetic -> latency-exposure-bound. R10 gets ALL THREE levers at once:
//   - job = (row-pair, quarter-tree): rp = t&63, q = t>>6 (WAVE-UNIFORM ->
//     readlane legal). Per thread: 5 top sig2 + 4x15 sig2 = 65 sig2 over
//     2 rows (R9: 128), chains 4 levels deep per pass (R9: 5+ fused).
//   - LDS: xT [32][130] f32 16.6KB + P [128][64] f16 16KB + lc 1KB = 34KB
//     -> 4 blocks/CU = 16 waves/CU (R9: 8) at launch_bounds(256,4).
//   - ILP=2 kept: sig2 evaluates both rows of the pair off one ds_read_b64.
// Pass p: quarter q writes chunk cols [16q,16q+16) = global leaves
// 64q+16p+j; Bf built from the matching s_lc entries. MFMA conventions
// byte-identical to verified R7/R8/R9: A k-group (lane>>4)*8, XOR swizzle
// ((r^(r>>3))&7)<<4 on 128B rows, C/D col=lane&15, row=(lane>>4)*4+reg.
// Node banking: ta = nodes 0..62 (lane=n, used for d<=5), tb = 63..126
// (lane=n-63, d6), t7 = quarter's 32 d7 nodes (thr[127+32q+(lane&31)],
// readlane at l7 = 8p+k).

#define NFEAT 32
#define NCLS  10
#define TPB   256
#define RPB   128          // rows per block
#define XPITCH 130         // padded f32 pitch, EVEN: row-pair b64 aligned
#define L2E   1.4426950408889634f

typedef _Float16 f16x8 __attribute__((ext_vector_type(8)));
typedef float    f32x4 __attribute__((ext_vector_type(4)));

__device__ __forceinline__ float fexp2(float z) {
#if __has_builtin(__builtin_amdgcn_exp2f)
  return __builtin_amdgcn_exp2f(z);
#else
  return exp2f(z);
#endif
}
__device__ __forceinline__ float frcp(float z) {
#if __has_builtin(__builtin_amdgcn_rcpf)
  return __builtin_amdgcn_rcpf(z);
#else
  return 1.0f / z;
#endif
}
__device__ __forceinline__ float rlf(float v, int lane) {
  return __int_as_float(__builtin_amdgcn_readlane(__float_as_int(v), lane));
}
__device__ __forceinline__ int rli(int v, int lane) {
  return __builtin_amdgcn_readlane(v, lane);
}

// Lane-resident node records; thresholds stored as tpow = 2^(thr*log2e).
struct NodeRegs {
  float ta, tb, t7;   // nodes 0..62 / 63..126 / quarter's 32 d7 nodes
  int   fa, fb, f7;
};

// Paired sigmoid for rows (2rp, 2rp+1):
//   a = 1/(1 + tpow*w);  pr = p*a;  pl = p - pr  (== p*(1-a)).
__device__ __forceinline__ void sig2(float tpow, int ft, const float* xT, int rp,
                                     float p0, float p1,
                                     float& l0, float& r0, float& l1, float& r1) {
  const float2 w = *(const float2*)&xT[ft * XPITCH + 2 * rp];  // ds_read_b64
  const float a0 = frcp(__builtin_fmaf(tpow, w.x, 1.0f));
  const float a1 = frcp(__builtin_fmaf(tpow, w.y, 1.0f));
  r0 = p0 * a0;  l0 = p0 - r0;
  r1 = p1 * a1;  l1 = p1 - r1;
}
__device__ __forceinline__ void evalA2(const NodeRegs& R, const float* xT, int n,
                                       int rp, float p0, float p1,
                                       float& l0, float& r0, float& l1, float& r1) {
  sig2(rlf(R.ta, n), rli(R.fa, n), xT, rp, p0, p1, l0, r0, l1, r1);
}
__device__ __forceinline__ void evalB2(const NodeRegs& R, const float* xT, int n,
                                       int rp, float p0, float p1,
                                       float& l0, float& r0, float& l1, float& r1) {
  sig2(rlf(R.tb, n - 63), rli(R.fb, n - 63), xT, rp, p0, p1, l0, r0, l1, r1);
}
// quarter-local d7 node at lane l7 (0..31): packed half2 per row, low = LEFT.
__device__ __forceinline__ void leafpair7x2(const NodeRegs& R, const float* xT,
                                            int l7, int rp, float p0, float p1,
                                            unsigned& u0, unsigned& u1) {
  float l0, r0, l1, r1;
  sig2(rlf(R.t7, l7), rli(R.f7, l7), xT, rp, p0, p1, l0, r0, l1, r1);
  const _Float16 hl0 = (_Float16)l0, hr0 = (_Float16)r0;
  const _Float16 hl1 = (_Float16)l1, hr1 = (_Float16)r1;
  u0 = ((unsigned)__builtin_bit_cast(unsigned short, hr0) << 16) |
        (unsigned)__builtin_bit_cast(unsigned short, hl0);
  u1 = ((unsigned)__builtin_bit_cast(unsigned short, hr1) << 16) |
        (unsigned)__builtin_bit_cast(unsigned short, hl1);
}

// Depth-4 subtree (16 leaves) for BOTH rows of the pair -> 4 swizzled b128.
// m = d4 node (<=34, bank A); d5 = 2m+1,2m+2 (<=70?? no: <=62, bank A);
// d6 = 4m+3..6 (63..126, bank B); d7 lane base l7b = 8p.
__device__ __forceinline__ void d4block2(const NodeRegs& R, const float* xT,
                                         int rp, int m, int l7b,
                                         float p0, float p1,
                                         char* rowp0, char* rowp1,
                                         int swz0, int swz1, int qb) {
  float al0, ar0, al1, ar1;
  evalA2(R, xT, m, rp, p0, p1, al0, ar0, al1, ar1);
  float bll0, blr0, bll1, blr1;
  evalA2(R, xT, 2 * m + 1, rp, al0, al1, bll0, blr0, bll1, blr1);
  float brl0, brr0, brl1, brr1;
  evalA2(R, xT, 2 * m + 2, rp, ar0, ar1, brl0, brr0, brl1, brr1);
  float c0l0, c0r0, c0l1, c0r1, c1l0, c1r0, c1l1, c1r1;
  float c2l0, c2r0, c2l1, c2r1, c3l0, c3r0, c3l1, c3r1;
  evalB2(R, xT, 4 * m + 3, rp, bll0, bll1, c0l0, c0r0, c0l1, c0r1);
  evalB2(R, xT, 4 * m + 4, rp, blr0, blr1, c1l0, c1r0, c1l1, c1r1);
  evalB2(R, xT, 4 * m + 5, rp, brl0, brl1, c2l0, c2r0, c2l1, c2r1);
  evalB2(R, xT, 4 * m + 6, rp, brr0, brr1, c3l0, c3r0, c3l1, c3r1);
  uint4 ua0, ua1, ub0, ub1;
  leafpair7x2(R, xT, l7b + 0, rp, c0l0, c0l1, ua0.x, ua1.x);
  leafpair7x2(R, xT, l7b + 1, rp, c0r0, c0r1, ua0.y, ua1.y);
  leafpair7x2(R, xT, l7b + 2, rp, c1l0, c1l1, ua0.z, ua1.z);
  leafpair7x2(R, xT, l7b + 3, rp, c1r0, c1r1, ua0.w, ua1.w);
  leafpair7x2(R, xT, l7b + 4, rp, c2l0, c2l1, ub0.x, ub1.x);
  leafpair7x2(R, xT, l7b + 5, rp, c2r0, c2r1, ub0.y, ub1.y);
  leafpair7x2(R, xT, l7b + 6, rp, c3l0, c3l1, ub0.z, ub1.z);
  leafpair7x2(R, xT, l7b + 7, rp, c3r0, c3r1, ub0.w, ub1.w);
  *(uint4*)(rowp0 + ((qb)      ^ swz0)) = ua0;
  *(uint4*)(rowp0 + ((qb + 16) ^ swz0)) = ub0;
  *(uint4*)(rowp1 + ((qb)      ^ swz1)) = ua1;
  *(uint4*)(rowp1 + ((qb + 16) ^ swz1)) = ub1;
}

__global__ __launch_bounds__(TPB, 4)
void dt_kernel(const float* __restrict__ x,
               const float* __restrict__ thr,
               const int*   __restrict__ feats,
               const int*   __restrict__ leafc,
               float*       __restrict__ out) {
  __shared__ __align__(16) float s_xT[NFEAT * XPITCH];  // w = 2^-x2 (16.6KB)
  __shared__ __align__(16) char  s_P[RPB * 128];        // P chunk f16 (16KB)
  __shared__ int s_lc[256];                             // leaf classes (1KB)

  const int t    = threadIdx.x;
  const int lane = t & 63;
  const int rp   = t & 63;                  // row-pair index 0..63
  const int q    = t >> 6;                  // quarter = wave id (UNIFORM)

  // --- lane-resident node records (tpow = 2^(thr*log2e)) ---
  NodeRegs R;
  R.ta = fexp2(thr[lane] * L2E);
  R.tb = fexp2(thr[63 + lane] * L2E);
  R.t7 = fexp2(thr[127 + 32 * q + (lane & 31)] * L2E);
  R.fa = feats[lane];
  R.fb = feats[63 + lane];
  R.f7 = feats[127 + 32 * q + (lane & 31)];

  // --- stage w = 2^(-x*log2e): coalesced float4, transposed ---
  const float4* xg = (const float4*)x + (size_t)blockIdx.x * (RPB * NFEAT / 4);
#pragma unroll
  for (int k = 0; k < 4; ++k) {
    const int i4 = k * TPB + t;             // 0..1023
    const float4 v = xg[i4];
    const int r  = i4 >> 3;
    const int c0 = (i4 & 7) * 4;
    s_xT[(c0 + 0) * XPITCH + r] = fexp2(-v.x * L2E);
    s_xT[(c0 + 1) * XPITCH + r] = fexp2(-v.y * L2E);
    s_xT[(c0 + 2) * XPITCH + r] = fexp2(-v.z * L2E);
    s_xT[(c0 + 3) * XPITCH + r] = fexp2(-v.w * L2E);
  }
  s_lc[t] = leafc[t];

  __syncthreads();

  // --- top path of quarter q: nodes 0, 1+(q>>1), 3+q, 7+2q, 8+2q ---
  float l0, r0, l1, r1;
  evalA2(R, s_xT, 0, rp, 1.0f, 1.0f, l0, r0, l1, r1);
  const float P1_0 = (q < 2) ? l0 : r0;
  const float P1_1 = (q < 2) ? l1 : r1;
  evalA2(R, s_xT, 1 + (q >> 1), rp, P1_0, P1_1, l0, r0, l1, r1);
  const float P2_0 = (q & 1) ? r0 : l0;
  const float P2_1 = (q & 1) ? r1 : l1;
  evalA2(R, s_xT, 3 + q, rp, P2_0, P2_1, l0, r0, l1, r1);
  const float P3L0 = l0, P3R0 = r0, P3L1 = l1, P3R1 = r1;
  float p40_0, p41_0, p42_0, p43_0, p40_1, p41_1, p42_1, p43_1;
  evalA2(R, s_xT, 7 + 2 * q, rp, P3L0, P3L1, p40_0, p41_0, p40_1, p41_1);
  evalA2(R, s_xT, 8 + 2 * q, rp, P3R0, P3R1, p42_0, p43_0, p42_1, p43_1);

  const int row0 = 2 * rp, row1 = row0 + 1;
  const int swz0 = ((row0 ^ (row0 >> 3)) & 7) << 4;
  const int swz1 = ((row1 ^ (row1 >> 3)) & 7) << 4;
  char* rowp0    = s_P + row0 * 128;
  char* rowp1    = s_P + row1 * 128;
  const int qb   = 32 * q;                  // this quarter's byte base in a row
  const int col16 = lane & 15;
  const int kgrpB = (lane >> 4) * 16;

  f32x4 acc0 = {0.f, 0.f, 0.f, 0.f};
  f32x4 acc1 = {0.f, 0.f, 0.f, 0.f};

#pragma unroll 1
  for (int p = 0; p < 4; ++p) {
    __syncthreads();                        // prev pass's MFMA reads done

    // --- DFS: d4 subtree m = 15+4q+p (16 leaves, both rows) ---
    const float A0 = (p == 0) ? p40_0 : (p == 1) ? p41_0 : (p == 2) ? p42_0 : p43_0;
    const float A1 = (p == 0) ? p40_1 : (p == 1) ? p41_1 : (p == 2) ? p42_1 : p43_1;
    d4block2(R, s_xT, rp, 15 + 4 * q + p, 8 * p, A0, A1,
             rowp0, rowp1, swz0, swz1, qb);

    __syncthreads();                        // P chunk ready

    // --- B onehot fragments: chunk col c=16Q'+j <-> leaf 64Q'+16p+j ---
    f16x8 Bf0, Bf1;
    {
      const int kb   = (lane >> 4) * 8;     // 0,8,16,24
      const int base = 64 * (kb >> 4) + 16 * p + (kb & 8);
      const int4 cA0 = *(const int4*)&s_lc[base];
      const int4 cB0 = *(const int4*)&s_lc[base + 4];
      uint4 u0;
      u0.x = ((cA0.x == col16) ? 0x3C00u : 0u) | (((cA0.y == col16) ? 0x3C00u : 0u) << 16);
      u0.y = ((cA0.z == col16) ? 0x3C00u : 0u) | (((cA0.w == col16) ? 0x3C00u : 0u) << 16);
      u0.z = ((cB0.x == col16) ? 0x3C00u : 0u) | (((cB0.y == col16) ? 0x3C00u : 0u) << 16);
      u0.w = ((cB0.z == col16) ? 0x3C00u : 0u) | (((cB0.w == col16) ? 0x3C00u : 0u) << 16);
      Bf0 = __builtin_bit_cast(f16x8, u0);
      const int4 cA1 = *(const int4*)&s_lc[128 + base];
      const int4 cB1 = *(const int4*)&s_lc[128 + base + 4];
      uint4 u1;
      u1.x = ((cA1.x == col16) ? 0x3C00u : 0u) | (((cA1.y == col16) ? 0x3C00u : 0u) << 16);
      u1.y = ((cA1.z == col16) ? 0x3C00u : 0u) | (((cA1.w == col16) ? 0x3C00u : 0u) << 16);
      u1.z = ((cB1.x == col16) ? 0x3C00u : 0u) | (((cB1.y == col16) ? 0x3C00u : 0u) << 16);
      u1.w = ((cB1.z == col16) ? 0x3C00u : 0u) | (((cB1.w == col16) ? 0x3C00u : 0u) << 16);
      Bf1 = __builtin_bit_cast(f16x8, u1);
    }

    // --- 2 row-tiles per wave x 2 K=32 chunks ---
#pragma unroll
    for (int i = 0; i < 2; ++i) {
      const int arow = (q * 2 + i) * 16 + col16;
      const int aswz = ((arow ^ (arow >> 3)) & 7) << 4;
      const char* ap = s_P + arow * 128;
      const f16x8 a0 = *(const f16x8*)(ap + ((kgrpB)      ^ aswz));
      const f16x8 a1 = *(const f16x8*)(ap + ((kgrpB + 64) ^ aswz));
      if (i == 0) {
        acc0 = __builtin_amdgcn_mfma_f32_16x16x32_f16(a0, Bf0, acc0, 0, 0, 0);
        acc0 = __builtin_amdgcn_mfma_f32_16x16x32_f16(a1, Bf1, acc0, 0, 0, 0);
      } else {
        acc1 = __builtin_amdgcn_mfma_f32_16x16x32_f16(a0, Bf0, acc1, 0, 0, 0);
        acc1 = __builtin_amdgcn_mfma_f32_16x16x32_f16(a1, Bf1, acc1, 0, 0, 0);
      }
    }
  }

  // --- epilogue: D layout col=lane&15, row=(lane>>4)*4+reg (verified) ---
  if (col16 < NCLS) {
    const int r4 = (lane >> 4) * 4;
#pragma unroll
    for (int i = 0; i < 2; ++i) {
      const size_t gr = (size_t)blockIdx.x * RPB + (q * 2 + i) * 16 + r4;
#pragma unroll
      for (int j = 0; j < 4; ++j) {
        out[(gr + j) * NCLS + col16] = (i == 0) ? acc0[j] : acc1[j];
      }
    }
  }
}

extern "C" void kernel_launch(void* const* d_in, const int* in_sizes, int n_in,
                              void* d_out, int out_size, void* d_ws, size_t ws_size,
                              hipStream_t stream) {
  const float* x     = (const float*)d_in[0];
  const float* thr   = (const float*)d_in[1];
  const int*   feats = (const int*)d_in[2];
  const int*   leafc = (const int*)d_in[3];
  float*       out   = (float*)d_out;

  const int B    = in_sizes[0] / NFEAT;        // 131072
  const int grid = B / RPB;                    // 1024

  dt_kernel<<<grid, TPB, 0, stream>>>(x, thr, feats, leafc, out);
}

// Round 8
// 80.163 us; speedup vs baseline: 1.0680x; 1.0113x over previous
//
#include <hip/hip_runtime.h>

// Soft decision tree DEPTH=8, 255 internal nodes (heap order), 256 leaves,
// 10 classes, B=131072, 32 feats. fp32 in/out.
//
// R11: multi-generation pipelining. Evidence: R8 (occupancy), R9 (issue
// counts halved), R10 (chains quartered) each moved only ~6% off ~25us;
// issue arithmetic says 5-6us -> the ~15us residual is PHASE-STALL exposure.
// Common cause: every kernel R4-R10 had grid == resident capacity (ONE
// generation), so all blocks ran their serial phase structure in lockstep
// with nothing to fill barrier/staging/epilogue stalls.
//   - RPB=32 -> grid 4096 = 4 generations at 4 blocks/CU: blocks at
//     different phases co-reside and fill each other's stalls.
//   - TWO barriers per block total (R10: 9): job = (row-pair rp=t&15,
//     sixteenth-subtree sec=t>>4); 19 sig2/thread (4 top + 15 subtree)
//     emits its 16 leaves x 2 rows; whole P [32][256] f16 (16KB) written
//     in ONE DFS phase; waves 0/1 then do one 16-row tile x K=256
//     (8 MFMAs) each; waves 2/3 retire after the P barrier.
//   - sec not wave-uniform -> nodes via LDS broadcast reads (s_nd int2:
//     {2^t2 bits, feat}); costs +19 wave-DS/wave vs readlane, absorbed.
//   - sig2 ILP=2 kept (one ds_read_b64 serves both rows of a pair).
// LDS = s_nd 2040 + s_xT 32x34 f32 4352 + s_P 16384 + s_lc 1024 = 23.8KB
// -> 4 blocks/CU at launch_bounds(256,4), VGPR <=128 (no spill risk).
// MFMA conventions byte-identical to verified R7-R10: A k-group (lane>>4)*8
// <-> B k-label, XOR swizzle ((r^(r>>3))&7)<<4 on 16B units, C/D
// col=lane&15, row=(lane>>4)*4+reg. P rows now 512B; swizzle flips bits
// 4-6 only -> stays within the row (bank period = 128B).
// Falsification: dur_us >= 79 kills the phase-stall theory too -> treat
// ~80 as practical floor (fill 43us + ~17us harness + kernel).

#define NFEAT 32
#define NCLS  10
#define TPB   256
#define RPB   32           // rows per block -> grid 4096 = 4 generations
#define XPITCH 34          // padded f32 pitch, EVEN: row-pair b64 aligned
#define L2E   1.4426950408889634f

typedef _Float16 f16x8 __attribute__((ext_vector_type(8)));
typedef float    f32x4 __attribute__((ext_vector_type(4)));

__device__ __forceinline__ float fexp2(float z) {
#if __has_builtin(__builtin_amdgcn_exp2f)
  return __builtin_amdgcn_exp2f(z);
#else
  return exp2f(z);
#endif
}
__device__ __forceinline__ float frcp(float z) {
#if __has_builtin(__builtin_amdgcn_rcpf)
  return __builtin_amdgcn_rcpf(z);
#else
  return 1.0f / z;
#endif
}

// Paired sigmoid for rows (2rp, 2rp+1); node record nd = {2^t2 bits, feat}.
//   a = 1/(1 + tpow*w);  pr = p*a;  pl = p - pr  (== p*(1-a)).
__device__ __forceinline__ void sig2(const int2 nd, const float* xT, int rp,
                                     float p0, float p1,
                                     float& l0, float& r0, float& l1, float& r1) {
  const float2 wv = *(const float2*)&xT[nd.y * XPITCH + 2 * rp];  // ds_read_b64
  const float tp = __int_as_float(nd.x);
  const float a0 = frcp(__builtin_fmaf(tp, wv.x, 1.0f));
  const float a1 = frcp(__builtin_fmaf(tp, wv.y, 1.0f));
  r0 = p0 * a0;  l0 = p0 - r0;
  r1 = p1 * a1;  l1 = p1 - r1;
}
// depth-7 node: packed half2 per row, low = LEFT leaf.
__device__ __forceinline__ void lp2(const int2 nd, const float* xT, int rp,
                                    float p0, float p1,
                                    unsigned& u0, unsigned& u1) {
  float l0, r0, l1, r1;
  sig2(nd, xT, rp, p0, p1, l0, r0, l1, r1);
  const _Float16 hl0 = (_Float16)l0, hr0 = (_Float16)r0;
  const _Float16 hl1 = (_Float16)l1, hr1 = (_Float16)r1;
  u0 = ((unsigned)__builtin_bit_cast(unsigned short, hr0) << 16) |
        (unsigned)__builtin_bit_cast(unsigned short, hl0);
  u1 = ((unsigned)__builtin_bit_cast(unsigned short, hr1) << 16) |
        (unsigned)__builtin_bit_cast(unsigned short, hl1);
}

__global__ __launch_bounds__(TPB, 4)
void dt_kernel(const float* __restrict__ x,
               const float* __restrict__ thr,
               const int*   __restrict__ feats,
               const int*   __restrict__ leafc,
               float*       __restrict__ out) {
  __shared__ __align__(8)  int2  s_nd[255];             // {2^t2, feat} (2040B)
  __shared__ __align__(16) float s_xT[NFEAT * XPITCH];  // w = 2^-x2 (4352B)
  __shared__ __align__(16) char  s_P[RPB * 512];        // P f16 (16KB)
  __shared__ int s_lc[256];                             // leaf classes (1KB)

  const int t    = threadIdx.x;
  const int lane = t & 63;
  const int rp   = t & 15;                  // row-pair index 0..15
  const int sec  = t >> 4;                  // sixteenth-subtree 0..15
  const int w    = t >> 6;                  // wave id 0..3

  // --- stage nodes (tpow = 2^(thr*log2e)), leaf classes, x ---
  if (t < 255) {
    s_nd[t] = make_int2(__float_as_int(fexp2(thr[t] * L2E)), feats[t]);
  }
  s_lc[t] = leafc[t];
  {
    const float4* xg = (const float4*)x + (size_t)blockIdx.x * (RPB * NFEAT / 4);
    const float4 v = xg[t];                 // one float4 per thread
    const int r  = t >> 3;                  // local row 0..31
    const int c0 = (t & 7) * 4;             // first feature column
    s_xT[(c0 + 0) * XPITCH + r] = fexp2(-v.x * L2E);
    s_xT[(c0 + 1) * XPITCH + r] = fexp2(-v.y * L2E);
    s_xT[(c0 + 2) * XPITCH + r] = fexp2(-v.z * L2E);
    s_xT[(c0 + 3) * XPITCH + r] = fexp2(-v.w * L2E);
  }

  __syncthreads();                          // barrier 1 of 2

  // --- top path: nodes 0, 1+(sec>>3), 3+(sec>>2), 7+(sec>>1) ---
  float l0, r0, l1, r1;
  sig2(s_nd[0], s_xT, rp, 1.0f, 1.0f, l0, r0, l1, r1);
  float p0 = (sec & 8) ? r0 : l0;
  float p1 = (sec & 8) ? r1 : l1;
  sig2(s_nd[1 + (sec >> 3)], s_xT, rp, p0, p1, l0, r0, l1, r1);
  p0 = (sec & 4) ? r0 : l0;  p1 = (sec & 4) ? r1 : l1;
  sig2(s_nd[3 + (sec >> 2)], s_xT, rp, p0, p1, l0, r0, l1, r1);
  p0 = (sec & 2) ? r0 : l0;  p1 = (sec & 2) ? r1 : l1;
  sig2(s_nd[7 + (sec >> 1)], s_xT, rp, p0, p1, l0, r0, l1, r1);
  p0 = (sec & 1) ? r0 : l0;  p1 = (sec & 1) ? r1 : l1;

  // --- d4 subtree, root n4 = 15+sec: 15 sig2 -> 16 leaves x 2 rows ---
  const int n4 = 15 + sec;
  float a_l0, a_r0, a_l1, a_r1;
  sig2(s_nd[n4], s_xT, rp, p0, p1, a_l0, a_r0, a_l1, a_r1);
  float b0_l0, b0_r0, b0_l1, b0_r1, b1_l0, b1_r0, b1_l1, b1_r1;
  sig2(s_nd[2 * n4 + 1], s_xT, rp, a_l0, a_l1, b0_l0, b0_r0, b0_l1, b0_r1);
  sig2(s_nd[2 * n4 + 2], s_xT, rp, a_r0, a_r1, b1_l0, b1_r0, b1_l1, b1_r1);
  float c0_l0, c0_r0, c0_l1, c0_r1, c1_l0, c1_r0, c1_l1, c1_r1;
  float c2_l0, c2_r0, c2_l1, c2_r1, c3_l0, c3_r0, c3_l1, c3_r1;
  sig2(s_nd[4 * n4 + 3], s_xT, rp, b0_l0, b0_l1, c0_l0, c0_r0, c0_l1, c0_r1);
  sig2(s_nd[4 * n4 + 4], s_xT, rp, b0_r0, b0_r1, c1_l0, c1_r0, c1_l1, c1_r1);
  sig2(s_nd[4 * n4 + 5], s_xT, rp, b1_l0, b1_l1, c2_l0, c2_r0, c2_l1, c2_r1);
  sig2(s_nd[4 * n4 + 6], s_xT, rp, b1_r0, b1_r1, c3_l0, c3_r0, c3_l1, c3_r1);
  uint4 ua0, ua1, ub0, ub1;                 // d7 nodes 8*n4+7.. = 127+8sec+k
  lp2(s_nd[8 * n4 + 7],  s_xT, rp, c0_l0, c0_l1, ua0.x, ua1.x);
  lp2(s_nd[8 * n4 + 8],  s_xT, rp, c0_r0, c0_r1, ua0.y, ua1.y);
  lp2(s_nd[8 * n4 + 9],  s_xT, rp, c1_l0, c1_l1, ua0.z, ua1.z);
  lp2(s_nd[8 * n4 + 10], s_xT, rp, c1_r0, c1_r1, ua0.w, ua1.w);
  lp2(s_nd[8 * n4 + 11], s_xT, rp, c2_l0, c2_l1, ub0.x, ub1.x);
  lp2(s_nd[8 * n4 + 12], s_xT, rp, c2_r0, c2_r1, ub0.y, ub1.y);
  lp2(s_nd[8 * n4 + 13], s_xT, rp, c3_l0, c3_l1, ub0.z, ub1.z);
  lp2(s_nd[8 * n4 + 14], s_xT, rp, c3_r0, c3_r1, ub0.w, ub1.w);

  // --- write 32B leaf span per row, swizzled (flips addr bits 4-6 only) ---
  {
    const int row0 = 2 * rp, row1 = row0 + 1;
    const int swz0 = ((row0 ^ (row0 >> 3)) & 7) << 4;
    const int swz1 = ((row1 ^ (row1 >> 3)) & 7) << 4;
    char* q0 = s_P + row0 * 512;
    char* q1 = s_P + row1 * 512;
    const int qb = 32 * sec;
    *(uint4*)(q0 + ((qb)      ^ swz0)) = ua0;
    *(uint4*)(q0 + ((qb + 16) ^ swz0)) = ub0;
    *(uint4*)(q1 + ((qb)      ^ swz1)) = ua1;
    *(uint4*)(q1 + ((qb + 16) ^ swz1)) = ub1;
  }

  __syncthreads();                          // barrier 2 of 2

  // --- waves 0,1: tile w (rows 16w..16w+16) x K=256; waves 2,3 retire ---
  if (w < 2) {
    const int col16 = lane & 15;
    const int kb    = (lane >> 4) * 8;      // k-group elem base
    const int arow  = 16 * w + col16;
    const int aswz  = ((arow ^ (arow >> 3)) & 7) << 4;
    const char* ap  = s_P + arow * 512;
    f32x4 acc = {0.f, 0.f, 0.f, 0.f};
#pragma unroll
    for (int c = 0; c < 8; ++c) {
      // B onehot fragment for leaves [32c, 32c+32)
      const int4 cA = *(const int4*)&s_lc[c * 32 + kb];
      const int4 cB = *(const int4*)&s_lc[c * 32 + kb + 4];
      uint4 u;
      u.x = ((cA.x == col16) ? 0x3C00u : 0u) | (((cA.y == col16) ? 0x3C00u : 0u) << 16);
      u.y = ((cA.z == col16) ? 0x3C00u : 0u) | (((cA.w == col16) ? 0x3C00u : 0u) << 16);
      u.z = ((cB.x == col16) ? 0x3C00u : 0u) | (((cB.y == col16) ? 0x3C00u : 0u) << 16);
      u.w = ((cB.z == col16) ? 0x3C00u : 0u) | (((cB.w == col16) ? 0x3C00u : 0u) << 16);
      const f16x8 Bf = __builtin_bit_cast(f16x8, u);
      const f16x8 a  = *(const f16x8*)(ap + ((64 * c + 2 * kb) ^ aswz));
      acc = __builtin_amdgcn_mfma_f32_16x16x32_f16(a, Bf, acc, 0, 0, 0);
    }
    // D layout col=lane&15, row=(lane>>4)*4+reg (verified)
    if (col16 < NCLS) {
      const size_t gr = (size_t)blockIdx.x * RPB + 16 * w + (lane >> 4) * 4;
#pragma unroll
      for (int j = 0; j < 4; ++j) {
        out[(gr + j) * NCLS + col16] = acc[j];
      }
    }
  }
}

extern "C" void kernel_launch(void* const* d_in, const int* in_sizes, int n_in,
                              void* d_out, int out_size, void* d_ws, size_t ws_size,
                              hipStream_t stream) {
  const float* x     = (const float*)d_in[0];
  const float* thr   = (const float*)d_in[1];
  const int*   feats = (const int*)d_in[2];
  const int*   leafc = (const int*)d_in[3];
  float*       out   = (float*)d_out;

  const int B    = in_sizes[0] / NFEAT;        // 131072
  const int grid = B / RPB;                    // 4096
  dt_kernel<<<grid, TPB, 0, stream>>>(x, thr, feats, leafc, out);
}